// Round 1
// baseline (218.921 us; speedup 1.0000x reference)
//
#include <hip/hip_runtime.h>
#include <hip/hip_bf16.h>

#define NB_MAX 8192
#define NTHR 256

__device__ __forceinline__ void get_grid(const float* __restrict__ cell,
                                         int& g0, int& g1, int& g2,
                                         float& d0, float& d1, float& d2) {
  d0 = cell[0]; d1 = cell[4]; d2 = cell[8];
  const float bl = (float)(5.2 + 1e-05);   // CUTOFF/BUCKETS + EXTRA_SPACE, f64 -> f32
  g0 = (int)floorf(d0 / bl) + 1;
  g1 = (int)floorf(d1 / bl) + 1;
  g2 = (int)floorf(d2 / bl) + 1;
}

__device__ __forceinline__ void atom_vec(const float* __restrict__ coord, int a,
                                         float d0, float d1, float d2,
                                         int g0, int g1, int g2,
                                         int& v0, int& v1, int& v2) {
  float x = coord[3 * a + 0], y = coord[3 * a + 1], z = coord[3 * a + 2];
  float fx = x / d0, fy = y / d1, fz = z / d2;
  v0 = (int)rintf(fx * (float)(g0 - 1));
  v1 = (int)rintf(fy * (float)(g1 - 1));
  v2 = (int)rintf(fz * (float)(g2 - 1));
}

// K1: frac out, bucket id per atom, histogram
__global__ void k_bucket_count(const float* __restrict__ coord,
                               const float* __restrict__ cell,
                               float* __restrict__ out_frac,
                               int* __restrict__ flat,
                               int* __restrict__ counts, int n) {
  int a = blockIdx.x * blockDim.x + threadIdx.x;
  if (a >= n) return;
  int g0, g1, g2; float d0, d1, d2;
  get_grid(cell, g0, g1, g2, d0, d1, d2);
  float x = coord[3 * a + 0], y = coord[3 * a + 1], z = coord[3 * a + 2];
  float fx = x / d0, fy = y / d1, fz = z / d2;
  out_frac[3 * a + 0] = fx;
  out_frac[3 * a + 1] = fy;
  out_frac[3 * a + 2] = fz;
  int v0 = (int)rintf(fx * (float)(g0 - 1));
  int v1 = (int)rintf(fy * (float)(g1 - 1));
  int v2 = (int)rintf(fz * (float)(g2 - 1));
  int b = v0 * (g1 * g2) + v1 * g1 + v2;   // reference scaling = (g1*g2, g1, 1)
  flat[a] = b;
  atomicAdd(&counts[b], 1);
}

// K2: single-block exclusive scan over buckets: cumcounts, pair offsets, total P
__global__ __launch_bounds__(1024) void k_scan_buckets(
    const float* __restrict__ cell,
    const int* __restrict__ counts,
    int* __restrict__ cumc,
    int* __restrict__ pairoff,
    int* __restrict__ scalars) {
  int g0, g1, g2; float d0, d1, d2;
  get_grid(cell, g0, g1, g2, d0, d1, d2);
  int nb = g0 * g1 * g2;
  const int T = 1024, IT = NB_MAX / 1024;
  __shared__ int sc[T], sp[T];
  int t = threadIdx.x;
  int base = t * IT;
  int cv[IT];
  int lc = 0, lp = 0;
  for (int i = 0; i < IT; ++i) {
    int idx = base + i;
    int c = (idx < nb) ? counts[idx] : 0;
    cv[i] = c;
    lc += c;
    lp += c * (c - 1) / 2;
  }
  sc[t] = lc; sp[t] = lp;
  __syncthreads();
  for (int off = 1; off < T; off <<= 1) {
    int vc = 0, vp = 0;
    if (t >= off) { vc = sc[t - off]; vp = sp[t - off]; }
    __syncthreads();
    sc[t] += vc; sp[t] += vp;
    __syncthreads();
  }
  int ec = sc[t] - lc, ep = sp[t] - lp;   // exclusive prefixes
  for (int i = 0; i < IT; ++i) {
    int idx = base + i;
    if (idx < nb) { cumc[idx] = ec; pairoff[idx] = ep; }
    ec += cv[i];
    ep += cv[i] * (cv[i] - 1) / 2;
  }
  if (t == T - 1) scalars[0] = sp[T - 1];  // total P (within-image pair count)
}

// K3: scatter atoms into bucket segments (unordered within bucket)
__global__ void k_scatter(const int* __restrict__ flat,
                          const int* __restrict__ cumc,
                          int* __restrict__ fill,
                          int* __restrict__ sorted, int n) {
  int a = blockIdx.x * blockDim.x + threadIdx.x;
  if (a >= n) return;
  int b = flat[a];
  int pos = cumc[b] + atomicAdd(&fill[b], 1);
  sorted[pos] = a;
}

// K4: insertion-sort each bucket's segment by atom index (-> stable order)
__global__ void k_sort_buckets(const float* __restrict__ cell,
                               const int* __restrict__ counts,
                               const int* __restrict__ cumc,
                               int* __restrict__ sorted) {
  int b = blockIdx.x * blockDim.x + threadIdx.x;
  int g0, g1, g2; float d0, d1, d2;
  get_grid(cell, g0, g1, g2, d0, d1, d2);
  int nb = g0 * g1 * g2;
  if (b >= nb) return;
  int c = counts[b];
  int s = cumc[b];
  for (int i = 1; i < c; ++i) {
    int key = sorted[s + i];
    int j = i - 1;
    while (j >= 0 && sorted[s + j] > key) {
      sorted[s + j + 1] = sorted[s + j];
      --j;
    }
    sorted[s + j + 1] = key;
  }
}

// K4b: within-image pairs. Per bucket with c>=2: for l=1..c-1, u=0..l-1
__global__ void k_pairs(const float* __restrict__ cell,
                        const int* __restrict__ counts,
                        const int* __restrict__ cumc,
                        const int* __restrict__ pairoff,
                        const int* __restrict__ scalars,
                        float* __restrict__ out) {
  int b = blockIdx.x * blockDim.x + threadIdx.x;
  int g0, g1, g2; float d0, d1, d2;
  get_grid(cell, g0, g1, g2, d0, d1, d2);
  int nb = g0 * g1 * g2;
  if (b >= nb) return;
  int c = counts[b];
  if (c < 2) return;
  int cum = cumc[b];
  int off = pairoff[b];
  int P = scalars[0];
  int k = 0;
  for (int l = 1; l < c; ++l) {
    for (int u = 0; u < l; ++u) {
      out[off + k] = (float)(cum + u);
      out[P + off + k] = (float)(cum + l);
      ++k;
    }
  }
}

// K5: permutation outputs
__global__ void k_perm(const int* __restrict__ sorted,
                       float* __restrict__ out_im,
                       float* __restrict__ out_at, int n) {
  int i = blockIdx.x * blockDim.x + threadIdx.x;
  if (i >= n) return;
  int a = sorted[i];
  out_im[i] = (float)a;
  out_at[a] = (float)i;
}

// K6: per-atom neighbor-run length S(a) = sum over 7 displacement buckets of counts
__global__ void k_runlen(const float* __restrict__ coord,
                         const float* __restrict__ cell,
                         const int* __restrict__ counts,
                         int* __restrict__ Sarr, int n) {
  int a = blockIdx.x * blockDim.x + threadIdx.x;
  if (a >= n) return;
  int g0, g1, g2; float d0, d1, d2;
  get_grid(cell, g0, g1, g2, d0, d1, d2);
  int v0, v1, v2;
  atom_vec(coord, a, d0, d1, d2, g0, g1, g2, v0, v1, v2);
  int S = 0;
  for (int m = 0; m < 7; ++m) {
    int dx = ((m >> 2) & 1) ? 0 : -1;
    int dy = ((m >> 1) & 1) ? 0 : -1;
    int dz = (m & 1) ? 0 : -1;
    int nx = v0 + dx; if (nx < 0) nx += g0;
    int ny = v1 + dy; if (ny < 0) ny += g1;
    int nz = v2 + dz; if (nz < 0) nz += g2;
    int nb_ = nx * (g1 * g2) + ny * g1 + nz;
    S += counts[nb_];
  }
  Sarr[a] = S;
}

// K7a: block partial sums of S
__global__ void k_partials(const int* __restrict__ Sarr,
                           int* __restrict__ blockpart, int n) {
  __shared__ int sm[NTHR];
  int t = threadIdx.x;
  int a = blockIdx.x * NTHR + t;
  sm[t] = (a < n) ? Sarr[a] : 0;
  __syncthreads();
  for (int off = NTHR / 2; off > 0; off >>= 1) {
    if (t < off) sm[t] += sm[t + off];
    __syncthreads();
  }
  if (t == 0) blockpart[blockIdx.x] = sm[0];
}

// K7b: single-block exclusive scan of block partials (up to 1024 blocks)
__global__ __launch_bounds__(1024) void k_scan_partials(
    const int* __restrict__ blockpart,
    int* __restrict__ blockoff,
    int* __restrict__ scalars, int nblocks) {
  const int T = 1024;
  __shared__ int sm[T];
  int t = threadIdx.x;
  int v = (t < nblocks) ? blockpart[t] : 0;
  sm[t] = v;
  __syncthreads();
  for (int off = 1; off < T; off <<= 1) {
    int x = 0;
    if (t >= off) x = sm[t - off];
    __syncthreads();
    sm[t] += x;
    __syncthreads();
  }
  blockoff[t] = sm[t] - v;               // exclusive
  if (t == T - 1) scalars[1] = sm[T - 1];  // total L (unused)
}

// K8: emit lower_between runs
__global__ void k_emit(const float* __restrict__ coord,
                       const float* __restrict__ cell,
                       const int* __restrict__ counts,
                       const int* __restrict__ cumc,
                       const int* __restrict__ Sarr,
                       const int* __restrict__ blockoff,
                       const int* __restrict__ scalars,
                       float* __restrict__ out, int n) {
  __shared__ int sm[NTHR];
  int t = threadIdx.x;
  int a = blockIdx.x * NTHR + t;
  int S = (a < n) ? Sarr[a] : 0;
  sm[t] = S;
  __syncthreads();
  for (int off = 1; off < NTHR; off <<= 1) {
    int x = 0;
    if (t >= off) x = sm[t - off];
    __syncthreads();
    sm[t] += x;
    __syncthreads();
  }
  int excl = sm[t] - S;
  if (a >= n) return;
  int g0, g1, g2; float d0, d1, d2;
  get_grid(cell, g0, g1, g2, d0, d1, d2);
  int v0, v1, v2;
  atom_vec(coord, a, d0, d1, d2, g0, g1, g2, v0, v1, v2);
  long base = 2L * (long)scalars[0] + (long)blockoff[blockIdx.x] + (long)excl;
  int k = 0;
  for (int m = 0; m < 7; ++m) {
    int dx = ((m >> 2) & 1) ? 0 : -1;
    int dy = ((m >> 1) & 1) ? 0 : -1;
    int dz = (m & 1) ? 0 : -1;
    int nx = v0 + dx; if (nx < 0) nx += g0;
    int ny = v1 + dy; if (ny < 0) ny += g1;
    int nz = v2 + dz; if (nz < 0) nz += g2;
    int nb_ = nx * (g1 * g2) + ny * g1 + nz;
    int c = counts[nb_];
    int cum = cumc[nb_];
    for (int j = 0; j < c; ++j) {
      out[base + k] = (float)(cum + j);
      ++k;
    }
  }
}

extern "C" void kernel_launch(void* const* d_in, const int* in_sizes, int n_in,
                              void* d_out, int out_size, void* d_ws, size_t ws_size,
                              hipStream_t stream) {
  const float* coord = (const float*)d_in[0];
  const float* cell = (const float*)d_in[1];
  float* out = (float*)d_out;
  int n = in_sizes[0] / 3;

  int* W = (int*)d_ws;
  int* counts = W;                         // NB_MAX
  int* fill = W + NB_MAX;                  // NB_MAX
  int* scalars = W + 2 * NB_MAX;           // 16: [0]=P, [1]=L
  int* cumc = W + 2 * NB_MAX + 16;         // NB_MAX
  int* pairoff = cumc + NB_MAX;            // NB_MAX
  int* flat = pairoff + NB_MAX;            // n
  int* sorted = flat + n;                  // n
  int* Sarr = sorted + n;                  // n
  int* blockpart = Sarr + n;               // 1024
  int* blockoff = blockpart + 1024;        // 1024

  // output chunk bases known on host: out = [2P | L | 3n | n | n]
  float* out_frac = out + (out_size - 5 * n);
  float* out_im = out + (out_size - 2 * n);
  float* out_at = out + (out_size - n);

  int nblocks = (n + NTHR - 1) / NTHR;

  // zero counts, fill, scalars (contiguous at ws start)
  hipMemsetAsync(d_ws, 0, (size_t)(2 * NB_MAX + 16) * sizeof(int), stream);

  k_bucket_count<<<nblocks, NTHR, 0, stream>>>(coord, cell, out_frac, flat, counts, n);
  k_scan_buckets<<<1, 1024, 0, stream>>>(cell, counts, cumc, pairoff, scalars);
  k_scatter<<<nblocks, NTHR, 0, stream>>>(flat, cumc, fill, sorted, n);
  k_sort_buckets<<<NB_MAX / NTHR, NTHR, 0, stream>>>(cell, counts, cumc, sorted);
  k_pairs<<<NB_MAX / NTHR, NTHR, 0, stream>>>(cell, counts, cumc, pairoff, scalars, out);
  k_perm<<<nblocks, NTHR, 0, stream>>>(sorted, out_im, out_at, n);
  k_runlen<<<nblocks, NTHR, 0, stream>>>(coord, cell, counts, Sarr, n);
  k_partials<<<nblocks, NTHR, 0, stream>>>(Sarr, blockpart, n);
  k_scan_partials<<<1, 1024, 0, stream>>>(blockpart, blockoff, scalars, nblocks);
  k_emit<<<nblocks, NTHR, 0, stream>>>(coord, cell, counts, cumc, Sarr, blockoff, scalars, out, n);
}

// Round 3
// 141.156 us; speedup vs baseline: 1.5509x; 1.5509x over previous
//
#include <hip/hip_runtime.h>
#include <hip/hip_bf16.h>

#define NB_MAX 8192
#define NTHR 256

__device__ __forceinline__ void get_grid(const float* __restrict__ cell,
                                         int& g0, int& g1, int& g2,
                                         float& d0, float& d1, float& d2) {
  d0 = cell[0]; d1 = cell[4]; d2 = cell[8];
  const float bl = (float)(5.2 + 1e-05);   // CUTOFF/BUCKETS + EXTRA_SPACE, f64 -> f32
  g0 = (int)floorf(d0 / bl) + 1;
  g1 = (int)floorf(d1 / bl) + 1;
  g2 = (int)floorf(d2 / bl) + 1;
}

__device__ __forceinline__ void atom_vec(const float* __restrict__ coord, int a,
                                         float d0, float d1, float d2,
                                         int g0, int g1, int g2,
                                         int& v0, int& v1, int& v2) {
  float x = coord[3 * a + 0], y = coord[3 * a + 1], z = coord[3 * a + 2];
  float fx = x / d0, fy = y / d1, fz = z / d2;
  v0 = (int)rintf(fx * (float)(g0 - 1));
  v1 = (int)rintf(fy * (float)(g1 - 1));
  v2 = (int)rintf(fz * (float)(g2 - 1));
}

// K1: frac out, bucket id per atom, histogram
__global__ void k_bucket_count(const float* __restrict__ coord,
                               const float* __restrict__ cell,
                               float* __restrict__ out_frac,
                               int* __restrict__ flat,
                               int* __restrict__ counts, int n) {
  int a = blockIdx.x * blockDim.x + threadIdx.x;
  if (a >= n) return;
  int g0, g1, g2; float d0, d1, d2;
  get_grid(cell, g0, g1, g2, d0, d1, d2);
  float x = coord[3 * a + 0], y = coord[3 * a + 1], z = coord[3 * a + 2];
  float fx = x / d0, fy = y / d1, fz = z / d2;
  out_frac[3 * a + 0] = fx;
  out_frac[3 * a + 1] = fy;
  out_frac[3 * a + 2] = fz;
  int v0 = (int)rintf(fx * (float)(g0 - 1));
  int v1 = (int)rintf(fy * (float)(g1 - 1));
  int v2 = (int)rintf(fz * (float)(g2 - 1));
  int b = v0 * (g1 * g2) + v1 * g1 + v2;   // reference scaling = (g1*g2, g1, 1)
  flat[a] = b;
  atomicAdd(&counts[b], 1);
}

// K2: single-block exclusive scan over buckets: cumcounts, pair offsets, total P
__global__ __launch_bounds__(1024) void k_scan_buckets(
    const float* __restrict__ cell,
    const int* __restrict__ counts,
    int* __restrict__ cumc,
    int* __restrict__ pairoff,
    int* __restrict__ scalars) {
  int g0, g1, g2; float d0, d1, d2;
  get_grid(cell, g0, g1, g2, d0, d1, d2);
  int nb = g0 * g1 * g2;
  const int T = 1024, IT = NB_MAX / 1024;
  __shared__ int sc[T], sp[T];
  int t = threadIdx.x;
  int base = t * IT;
  int cv[IT];
  int lc = 0, lp = 0;
  for (int i = 0; i < IT; ++i) {
    int idx = base + i;
    int c = (idx < nb) ? counts[idx] : 0;
    cv[i] = c;
    lc += c;
    lp += c * (c - 1) / 2;
  }
  sc[t] = lc; sp[t] = lp;
  __syncthreads();
  for (int off = 1; off < T; off <<= 1) {
    int vc = 0, vp = 0;
    if (t >= off) { vc = sc[t - off]; vp = sp[t - off]; }
    __syncthreads();
    sc[t] += vc; sp[t] += vp;
    __syncthreads();
  }
  int ec = sc[t] - lc, ep = sp[t] - lp;   // exclusive prefixes
  for (int i = 0; i < IT; ++i) {
    int idx = base + i;
    if (idx < nb) { cumc[idx] = ec; pairoff[idx] = ep; }
    ec += cv[i];
    ep += cv[i] * (cv[i] - 1) / 2;
  }
  if (t == T - 1) scalars[0] = sp[T - 1];  // total P (within-image pair count)
}

// K3: scatter atoms into bucket segments (unordered within bucket)
__global__ void k_scatter(const int* __restrict__ flat,
                          const int* __restrict__ cumc,
                          int* __restrict__ fill,
                          int* __restrict__ sorted, int n) {
  int a = blockIdx.x * blockDim.x + threadIdx.x;
  if (a >= n) return;
  int b = flat[a];
  int pos = cumc[b] + atomicAdd(&fill[b], 1);
  sorted[pos] = a;
}

// K4: wave-per-bucket rank sort (atom ids distinct -> unique ranks).
// Block = 4 waves = 4 buckets. Fallback to serial insertion for c > 64.
__global__ void k_sort_buckets(const float* __restrict__ cell,
                               const int* __restrict__ counts,
                               const int* __restrict__ cumc,
                               int* __restrict__ sorted) {
  int lane = threadIdx.x & 63;
  int b = blockIdx.x * 4 + (threadIdx.x >> 6);
  int g0, g1, g2; float d0, d1, d2;
  get_grid(cell, g0, g1, g2, d0, d1, d2);
  int nb = g0 * g1 * g2;
  if (b >= nb) return;
  int c = counts[b];
  if (c < 2) return;
  int s = cumc[b];
  if (c <= 64) {
    int val = (lane < c) ? sorted[s + lane] : 0x7fffffff;
    int rank = 0;
    for (int j = 0; j < c; ++j) {
      int other = __shfl(val, j);
      rank += (other < val) ? 1 : 0;
    }
    if (lane < c) sorted[s + rank] = val;
  } else if (lane == 0) {
    for (int i = 1; i < c; ++i) {
      int key = sorted[s + i];
      int j = i - 1;
      while (j >= 0 && sorted[s + j] > key) {
        sorted[s + j + 1] = sorted[s + j];
        --j;
      }
      sorted[s + j + 1] = key;
    }
  }
}

// K4b: wave-per-bucket within-image pairs. Emission order: for l=1..c-1, u=0..l-1
// i.e. pair index k = l(l-1)/2 + u. Lanes stride over k.
__global__ void k_pairs(const float* __restrict__ cell,
                        const int* __restrict__ counts,
                        const int* __restrict__ cumc,
                        const int* __restrict__ pairoff,
                        const int* __restrict__ scalars,
                        float* __restrict__ out) {
  int lane = threadIdx.x & 63;
  int b = blockIdx.x * 4 + (threadIdx.x >> 6);
  int g0, g1, g2; float d0, d1, d2;
  get_grid(cell, g0, g1, g2, d0, d1, d2);
  int nb = g0 * g1 * g2;
  if (b >= nb) return;
  int c = counts[b];
  if (c < 2) return;
  int cum = cumc[b];
  int off = pairoff[b];
  int P = scalars[0];
  int np = c * (c - 1) / 2;
  for (int k = lane; k < np; k += 64) {
    // decode l: largest l with l(l-1)/2 <= k
    int l = (int)((1.0f + sqrtf(1.0f + 8.0f * (float)k)) * 0.5f);
    while (l * (l - 1) / 2 > k) --l;
    while ((l + 1) * l / 2 <= k) ++l;
    int u = k - l * (l - 1) / 2;
    out[off + k] = (float)(cum + u);
    out[P + off + k] = (float)(cum + l);
  }
}

// K5: permutation outputs
__global__ void k_perm(const int* __restrict__ sorted,
                       float* __restrict__ out_im,
                       float* __restrict__ out_at, int n) {
  int i = blockIdx.x * blockDim.x + threadIdx.x;
  if (i >= n) return;
  int a = sorted[i];
  out_im[i] = (float)a;
  out_at[a] = (float)i;
}

// K6: per-atom neighbor-run length S(a) + block partial sums (fused)
__global__ void k_runlen(const float* __restrict__ coord,
                         const float* __restrict__ cell,
                         const int* __restrict__ counts,
                         int* __restrict__ Sarr,
                         int* __restrict__ blockpart, int n) {
  __shared__ int sm[NTHR];
  int t = threadIdx.x;
  int a = blockIdx.x * NTHR + t;
  int S = 0;
  if (a < n) {
    int g0, g1, g2; float d0, d1, d2;
    get_grid(cell, g0, g1, g2, d0, d1, d2);
    int v0, v1, v2;
    atom_vec(coord, a, d0, d1, d2, g0, g1, g2, v0, v1, v2);
    for (int m = 0; m < 7; ++m) {
      int dx = ((m >> 2) & 1) ? 0 : -1;
      int dy = ((m >> 1) & 1) ? 0 : -1;
      int dz = (m & 1) ? 0 : -1;
      int nx = v0 + dx; if (nx < 0) nx += g0;
      int ny = v1 + dy; if (ny < 0) ny += g1;
      int nz = v2 + dz; if (nz < 0) nz += g2;
      int nb_ = nx * (g1 * g2) + ny * g1 + nz;
      S += counts[nb_];
    }
    Sarr[a] = S;
  }
  sm[t] = S;
  __syncthreads();
  for (int off = NTHR / 2; off > 0; off >>= 1) {
    if (t < off) sm[t] += sm[t + off];
    __syncthreads();
  }
  if (t == 0) blockpart[blockIdx.x] = sm[0];
}

// K7: single-block exclusive scan of block partials (up to 1024 blocks)
__global__ __launch_bounds__(1024) void k_scan_partials(
    const int* __restrict__ blockpart,
    int* __restrict__ blockoff,
    int* __restrict__ scalars, int nblocks) {
  const int T = 1024;
  __shared__ int sm[T];
  int t = threadIdx.x;
  int v = (t < nblocks) ? blockpart[t] : 0;
  sm[t] = v;
  __syncthreads();
  for (int off = 1; off < T; off <<= 1) {
    int x = 0;
    if (t >= off) x = sm[t - off];
    __syncthreads();
    sm[t] += x;
    __syncthreads();
  }
  blockoff[t] = sm[t] - v;               // exclusive
  if (t == T - 1) scalars[1] = sm[T - 1];  // total L (unused)
}

// K8: emit lower_between runs
__global__ void k_emit(const float* __restrict__ coord,
                       const float* __restrict__ cell,
                       const int* __restrict__ counts,
                       const int* __restrict__ cumc,
                       const int* __restrict__ Sarr,
                       const int* __restrict__ blockoff,
                       const int* __restrict__ scalars,
                       float* __restrict__ out, int n) {
  __shared__ int sm[NTHR];
  int t = threadIdx.x;
  int a = blockIdx.x * NTHR + t;
  int S = (a < n) ? Sarr[a] : 0;
  sm[t] = S;
  __syncthreads();
  for (int off = 1; off < NTHR; off <<= 1) {
    int x = 0;
    if (t >= off) x = sm[t - off];
    __syncthreads();
    sm[t] += x;
    __syncthreads();
  }
  int excl = sm[t] - S;
  if (a >= n) return;
  int g0, g1, g2; float d0, d1, d2;
  get_grid(cell, g0, g1, g2, d0, d1, d2);
  int v0, v1, v2;
  atom_vec(coord, a, d0, d1, d2, g0, g1, g2, v0, v1, v2);
  long base = 2L * (long)scalars[0] + (long)blockoff[blockIdx.x] + (long)excl;
  int k = 0;
  for (int m = 0; m < 7; ++m) {
    int dx = ((m >> 2) & 1) ? 0 : -1;
    int dy = ((m >> 1) & 1) ? 0 : -1;
    int dz = (m & 1) ? 0 : -1;
    int nx = v0 + dx; if (nx < 0) nx += g0;
    int ny = v1 + dy; if (ny < 0) ny += g1;
    int nz = v2 + dz; if (nz < 0) nz += g2;
    int nb_ = nx * (g1 * g2) + ny * g1 + nz;
    int c = counts[nb_];
    int cum = cumc[nb_];
    for (int j = 0; j < c; ++j) {
      out[base + k] = (float)(cum + j);
      ++k;
    }
  }
}

extern "C" void kernel_launch(void* const* d_in, const int* in_sizes, int n_in,
                              void* d_out, int out_size, void* d_ws, size_t ws_size,
                              hipStream_t stream) {
  const float* coord = (const float*)d_in[0];
  const float* cell = (const float*)d_in[1];
  float* out = (float*)d_out;
  int n = in_sizes[0] / 3;

  int* W = (int*)d_ws;
  int* counts = W;                         // NB_MAX
  int* fill = W + NB_MAX;                  // NB_MAX
  int* scalars = W + 2 * NB_MAX;           // 16: [0]=P, [1]=L
  int* cumc = W + 2 * NB_MAX + 16;         // NB_MAX
  int* pairoff = cumc + NB_MAX;            // NB_MAX
  int* flat = pairoff + NB_MAX;            // n
  int* sorted = flat + n;                  // n
  int* Sarr = sorted + n;                  // n
  int* blockpart = Sarr + n;               // 1024
  int* blockoff = blockpart + 1024;        // 1024

  // output chunk bases known on host: out = [2P | L | 3n | n | n]
  float* out_frac = out + (out_size - 5 * n);
  float* out_im = out + (out_size - 2 * n);
  float* out_at = out + (out_size - n);

  int nblocks = (n + NTHR - 1) / NTHR;

  // zero counts, fill, scalars (contiguous at ws start)
  hipMemsetAsync(d_ws, 0, (size_t)(2 * NB_MAX + 16) * sizeof(int), stream);

  k_bucket_count<<<nblocks, NTHR, 0, stream>>>(coord, cell, out_frac, flat, counts, n);
  k_scan_buckets<<<1, 1024, 0, stream>>>(cell, counts, cumc, pairoff, scalars);
  k_scatter<<<nblocks, NTHR, 0, stream>>>(flat, cumc, fill, sorted, n);
  k_sort_buckets<<<NB_MAX / 4, 256, 0, stream>>>(cell, counts, cumc, sorted);      // 4 buckets/block (1 per wave)
  k_pairs<<<NB_MAX / 4, 256, 0, stream>>>(cell, counts, cumc, pairoff, scalars, out);
  k_perm<<<nblocks, NTHR, 0, stream>>>(sorted, out_im, out_at, n);
  k_runlen<<<nblocks, NTHR, 0, stream>>>(coord, cell, counts, Sarr, blockpart, n);
  k_scan_partials<<<1, 1024, 0, stream>>>(blockpart, blockoff, scalars, nblocks);
  k_emit<<<nblocks, NTHR, 0, stream>>>(coord, cell, counts, cumc, Sarr, blockoff, scalars, out, n);
}